// Round 4
// baseline (106.806 us; speedup 1.0000x reference)
//
#include <hip/hip_runtime.h>
#include <math.h>

// Problem constants (fixed by reference: H=256, N=64, CH=1, L=2048)
#define NH   256
#define NN   64
#define LSEQ 2048
#define RS   72       // LDS row stride in bf16 elements (144 B: 16B-aligned rows; 36 dwords ≡ 4 mod 32 -> b128 phases tile banks)
#define PSZ  4608     // elems per 64-row component array (64*72), 9216 B
#define GSZ  2304     // elems per 32-row component array (32*72), 4608 B
#define NTH  1024

typedef __attribute__((ext_vector_type(8))) short short8;     // 8 bf16 (MFMA A/B frag)
typedef __attribute__((ext_vector_type(4))) float float4_t;   // 16x16 MFMA C/D frag
typedef __attribute__((ext_vector_type(16))) float float16_t; // 32x32 MFMA C/D frag
typedef unsigned short u16;

#define MFMA(a,b,c)   __builtin_amdgcn_mfma_f32_16x16x32_bf16((a),(b),(c),0,0,0)
#define MFMA32(a,b,c) __builtin_amdgcn_mfma_f32_32x32x16_bf16((a),(b),(c),0,0,0)
#define PERM_HI 0x07060302u   // [a.hi16 | b.hi16]

// value v -> hi bits (bf16<<16) and lo bits (f32 of v-hi; its top16 = lo bf16)
static __device__ __forceinline__ void split2(float v, unsigned& hb, unsigned& lb) {
    hb = __float_as_uint(v) & 0xffff0000u;
    lb = __float_as_uint(v - __uint_as_float(hb));
}
// reconstruct f32 from separated hi/lo bf16 arrays
static __device__ __forceinline__ float ld2(const u16* hp, const u16* lp, int idx) {
    return __uint_as_float((unsigned)hp[idx] << 16)
         + __uint_as_float((unsigned)lp[idx] << 16);
}

// build hi/lo short8 frags from 8 f32 bit patterns (m1 global path only)
static __device__ __forceinline__ void frag_vals(const unsigned* e, short8& hi, short8& lo) {
    unsigned lb[8];
#pragma unroll
    for (int m = 0; m < 8; ++m) {
        unsigned hv = e[m] & 0xffff0000u;
        lb[m] = __float_as_uint(__uint_as_float(e[m]) - __uint_as_float(hv));
    }
    union { short8 s; unsigned u[4]; } H, L;
#pragma unroll
    for (int m = 0; m < 4; ++m) {
        H.u[m] = __builtin_amdgcn_perm(e[2*m+1],  e[2*m],  PERM_HI);
        L.u[m] = __builtin_amdgcn_perm(lb[2*m+1], lb[2*m], PERM_HI);
    }
    hi = H.s; lo = L.s;
}

// One 16x16 tile of complex P = A*B, K=64. A and B-transpose are separated
// hi/lo bf16 component arrays: [rh | rl | ih | il] each ASZ/BSZ elems apart.
template<int ASZ, int BSZ, bool IMAG>
static __device__ __forceinline__ void cmm_tile(
    const u16* __restrict__ Ab, const u16* __restrict__ Bb,
    int arow, int bcol, int fq,
    float4_t& accP, float4_t& accN, float4_t& accI1, float4_t& accI2)
{
#pragma unroll
    for (int ks = 0; ks < 2; ++ks) {
        const int k0 = ks*32 + fq*8;
        const u16* ap = Ab + arow*RS + k0;
        const u16* bp = Bb + bcol*RS + k0;
        short8 Arh = *(const short8*)(ap);
        short8 Arl = *(const short8*)(ap + ASZ);
        short8 Aih = *(const short8*)(ap + 2*ASZ);
        short8 Ail = *(const short8*)(ap + 3*ASZ);
        short8 Brh = *(const short8*)(bp);
        short8 Brl = *(const short8*)(bp + BSZ);
        short8 Bih = *(const short8*)(bp + 2*BSZ);
        short8 Bil = *(const short8*)(bp + 3*BSZ);
        accP = MFMA(Arh, Brh, accP); accP = MFMA(Arh, Brl, accP); accP = MFMA(Arl, Brh, accP);
        accN = MFMA(Aih, Bih, accN); accN = MFMA(Aih, Bil, accN); accN = MFMA(Ail, Bih, accN);
        if (IMAG) {
            accI1 = MFMA(Arh, Bih, accI1); accI1 = MFMA(Arh, Bil, accI1); accI1 = MFMA(Arl, Bih, accI1);
            accI2 = MFMA(Aih, Brh, accI2); accI2 = MFMA(Aih, Brl, accI2); accI2 = MFMA(Ail, Brh, accI2);
        }
    }
}

// Paired tiles: one A-row panel (arow), two B cols (bcol0, bcol0+16).
// A-frags loaded ONCE and reused -> 24 reads per wave for 2 tiles (vs 32).
template<int ASZ, int BSZ>
static __device__ __forceinline__ void cmm_pair(
    const u16* __restrict__ Ab, const u16* __restrict__ Bb,
    int arow, int bcol0, int fq,
    float4_t& P0, float4_t& N0, float4_t& I10, float4_t& I20,
    float4_t& P1, float4_t& N1, float4_t& I11, float4_t& I21)
{
#pragma unroll
    for (int ks = 0; ks < 2; ++ks) {
        const int k0 = ks*32 + fq*8;
        const u16* ap = Ab + arow*RS + k0;
        short8 Arh = *(const short8*)(ap);
        short8 Arl = *(const short8*)(ap + ASZ);
        short8 Aih = *(const short8*)(ap + 2*ASZ);
        short8 Ail = *(const short8*)(ap + 3*ASZ);
        {
            const u16* bp0 = Bb + bcol0*RS + k0;
            short8 Brh = *(const short8*)(bp0);
            short8 Brl = *(const short8*)(bp0 + BSZ);
            short8 Bih = *(const short8*)(bp0 + 2*BSZ);
            short8 Bil = *(const short8*)(bp0 + 3*BSZ);
            P0 = MFMA(Arh, Brh, P0); P0 = MFMA(Arh, Brl, P0); P0 = MFMA(Arl, Brh, P0);
            N0 = MFMA(Aih, Bih, N0); N0 = MFMA(Aih, Bil, N0); N0 = MFMA(Ail, Bih, N0);
            I10 = MFMA(Arh, Bih, I10); I10 = MFMA(Arh, Bil, I10); I10 = MFMA(Arl, Bih, I10);
            I20 = MFMA(Aih, Brh, I20); I20 = MFMA(Aih, Brl, I20); I20 = MFMA(Ail, Brh, I20);
        }
        {
            const u16* bp1 = Bb + (bcol0 + 16)*RS + k0;
            short8 Brh = *(const short8*)(bp1);
            short8 Brl = *(const short8*)(bp1 + BSZ);
            short8 Bih = *(const short8*)(bp1 + 2*BSZ);
            short8 Bil = *(const short8*)(bp1 + 3*BSZ);
            P1 = MFMA(Arh, Brh, P1); P1 = MFMA(Arh, Brl, P1); P1 = MFMA(Arl, Brh, P1);
            N1 = MFMA(Aih, Bih, N1); N1 = MFMA(Aih, Bil, N1); N1 = MFMA(Ail, Bih, N1);
            I11 = MFMA(Arh, Bih, I11); I11 = MFMA(Arh, Bil, I11); I11 = MFMA(Arl, Bih, I11);
            I21 = MFMA(Aih, Brh, I21); I21 = MFMA(Aih, Brl, I21); I21 = MFMA(Ail, Brh, I21);
        }
    }
}

// 32x32 complex tile, K=64, via mfma_f32_32x32x16_bf16 (4 k-steps).
// A: lane row = arow (l&31-based), k = ks*16 + (l>>5)*8. B symmetric from Bt.
// 32 B read per complex output vs 48 B for paired 16x16.
template<int ASZ, int BSZ>
static __device__ __forceinline__ void cmm32_tile(
    const u16* __restrict__ Ab, const u16* __restrict__ Bb,
    int arow, int bcol, int khalf,
    float16_t& P, float16_t& N, float16_t& I1, float16_t& I2)
{
#pragma unroll
    for (int ks = 0; ks < 4; ++ks) {
        const int k0 = ks*16 + khalf;
        const u16* ap = Ab + arow*RS + k0;
        const u16* bp = Bb + bcol*RS + k0;
        short8 Arh = *(const short8*)(ap);
        short8 Arl = *(const short8*)(ap + ASZ);
        short8 Aih = *(const short8*)(ap + 2*ASZ);
        short8 Ail = *(const short8*)(ap + 3*ASZ);
        short8 Brh = *(const short8*)(bp);
        short8 Brl = *(const short8*)(bp + BSZ);
        short8 Bih = *(const short8*)(bp + 2*BSZ);
        short8 Bil = *(const short8*)(bp + 3*BSZ);
        P = MFMA32(Arh, Brh, P); P = MFMA32(Arh, Brl, P); P = MFMA32(Arl, Brh, P);
        N = MFMA32(Aih, Bih, N); N = MFMA32(Aih, Bil, N); N = MFMA32(Ail, Bih, N);
        I1 = MFMA32(Arh, Bih, I1); I1 = MFMA32(Arh, Bil, I1); I1 = MFMA32(Arl, Bih, I1);
        I2 = MFMA32(Aih, Brh, I2); I2 = MFMA32(Aih, Brl, I2); I2 = MFMA32(Ail, Brh, I2);
    }
}

// store complex values p_r/p_i (16x16 C-frag rows) into BOTH P views.
static __device__ __forceinline__ void store_P_vals(
    u16* XR, u16* XT, int ti, int bcol, int fq,
    const float* p_r, const float* p_i)
{
    unsigned hR[4], lR[4], hI[4], lI[4];
#pragma unroll
    for (int r = 0; r < 4; ++r) {
        split2(p_r[r], hR[r], lR[r]);
        split2(p_i[r], hI[r], lI[r]);
        int row = ti*16 + fq*4 + r;
        XR[row*RS + bcol]         = (u16)(hR[r] >> 16);
        XR[PSZ + row*RS + bcol]   = (u16)(lR[r] >> 16);
        XR[2*PSZ + row*RS + bcol] = (u16)(hI[r] >> 16);
        XR[3*PSZ + row*RS + bcol] = (u16)(lI[r] >> 16);
    }
    int tb = bcol*RS + ti*16 + fq*4;
    uint2 w;
    w.x = __builtin_amdgcn_perm(hR[1], hR[0], PERM_HI);
    w.y = __builtin_amdgcn_perm(hR[3], hR[2], PERM_HI);
    *(uint2*)&XT[tb] = w;
    w.x = __builtin_amdgcn_perm(lR[1], lR[0], PERM_HI);
    w.y = __builtin_amdgcn_perm(lR[3], lR[2], PERM_HI);
    *(uint2*)&XT[PSZ + tb] = w;
    w.x = __builtin_amdgcn_perm(hI[1], hI[0], PERM_HI);
    w.y = __builtin_amdgcn_perm(hI[3], hI[2], PERM_HI);
    *(uint2*)&XT[2*PSZ + tb] = w;
    w.x = __builtin_amdgcn_perm(lI[1], lI[0], PERM_HI);
    w.y = __builtin_amdgcn_perm(lI[3], lI[2], PERM_HI);
    *(uint2*)&XT[3*PSZ + tb] = w;
}

// store 32x32 C-frag (16 regs: col=lane&31, row=(g&3)+8*(g>>2)+4*(lane>>5))
// into BOTH views. XR: scalar b16; XT: 4 consecutive rows per reg-quad -> b64.
static __device__ __forceinline__ void store_P_vals32(
    u16* XR, u16* XT, int trow, int tcol, int lane,
    const float16_t& vR, const float16_t& vI)
{
    const int col = tcol + (lane & 31);
    const int hi4 = (lane >> 5) * 4;
#pragma unroll
    for (int q = 0; q < 4; ++q) {
        unsigned hR[4], lR[4], hI[4], lI[4];
#pragma unroll
        for (int rr = 0; rr < 4; ++rr) {
            const int g = 4*q + rr;
            split2(vR[g], hR[rr], lR[rr]);
            split2(vI[g], hI[rr], lI[rr]);
            const int row = trow + rr + 8*q + hi4;
            XR[row*RS + col]         = (u16)(hR[rr] >> 16);
            XR[PSZ + row*RS + col]   = (u16)(lR[rr] >> 16);
            XR[2*PSZ + row*RS + col] = (u16)(hI[rr] >> 16);
            XR[3*PSZ + row*RS + col] = (u16)(lI[rr] >> 16);
        }
        const int tb = col*RS + trow + 8*q + hi4;   // 8B-aligned
        uint2 w;
        w.x = __builtin_amdgcn_perm(hR[1], hR[0], PERM_HI);
        w.y = __builtin_amdgcn_perm(hR[3], hR[2], PERM_HI);
        *(uint2*)&XT[tb] = w;
        w.x = __builtin_amdgcn_perm(lR[1], lR[0], PERM_HI);
        w.y = __builtin_amdgcn_perm(lR[3], lR[2], PERM_HI);
        *(uint2*)&XT[PSZ + tb] = w;
        w.x = __builtin_amdgcn_perm(hI[1], hI[0], PERM_HI);
        w.y = __builtin_amdgcn_perm(hI[3], hI[2], PERM_HI);
        *(uint2*)&XT[2*PSZ + tb] = w;
        w.x = __builtin_amdgcn_perm(lI[1], lI[0], PERM_HI);
        w.y = __builtin_amdgcn_perm(lI[3], lI[2], PERM_HI);
        *(uint2*)&XT[3*PSZ + tb] = w;
    }
}

// k[h, 64j+i] = Re( g_j . x_i ),  g_j = c^T (dA^64)^j,  x_i = dA^i dB
// Cubic Newton: X1 = I + (dt/2)A; Y = Ab*X1; V = X1*Y; X2 = 3X1 - 3V + VY.
// P = dA = 2*X2 - I folded into m3 epilogue.
// dB = dt/2 (dA b + b): u = dA*b, then x0 = dt/2(u+b), x1 = dt/2(dA u + u).
// Ladder: 9 squarings to dA^512 on waves 0-3 (32x32 MFMA tiles, 1/SIMD);
// riders run CONCURRENTLY on waves 8-15: X-rounds C=2..32 at s=2..6,
// G-rounds C=1,2,4 at s=7..9; tail: 3 chained dA^512 G-steps + K tiles.
__global__ __launch_bounds__(NTH, 4) void ssm_kernel(
    const float* __restrict__ Ag,
    const float* __restrict__ Bg,
    const float* __restrict__ Cg,
    const float* __restrict__ LogDt,
    float* __restrict__ outp)
{
    __shared__ __align__(16) unsigned char lds[130048];
    u16* XR = (u16*)(lds);            // P row-major: rh,rl,ih,il (4 x 9216 B)
    u16* XT = (u16*)(lds +  36864);   // P transposed: rh,rl,ih,il
    u16* XF = (u16*)(lds +  73728);   // Xf[v][q] = x_v[q]; aliased as U = Y^T in Newton
    u16* Gm = (u16*)(lds + 110592);   // G[j][q] = g_j[q], 32 rows (4 x 4608 B)
    float* bvr = (float*)(lds + 129024);
    float* bvi = (float*)(lds + 129280);
    float* urr = (float*)(lds + 129536);   // u = dA*b scratch
    float* uri = (float*)(lds + 129792);

    const int t    = threadIdx.x;
    const int lane = t & 63;
    const int wv   = t >> 6;                 // 0..15
    const int fm   = lane & 15, fq = lane >> 4;
    const int h    = blockIdx.x;

    // paired-tile mapping (waves 0-7): row band tip, col halves tjp*32 + {0,16}
    const int tip  = wv >> 1, tjp = wv & 1;
    const int parow = tip*16 + fm;
    const int pb0   = tjp*32 + fm;
    const int pb1   = pb0 + 16;

    // 32x32 squaring mapping (waves 0-3): tile (ti2, tj2)
    const int ti2 = (wv >> 1) & 1, tj2 = wv & 1;
    const int arow32 = ti2*32 + (lane & 31);
    const int bcol32 = tj2*32 + (lane & 31);
    const int khalf  = (lane >> 5) * 8;

    const float dt  = expf(LogDt[h]);
    const float hdt = 0.5f * dt;

    const float2* A2 = (const float2*)(Ag + (size_t)h * NN * NN * 2);
    const float4_t z4 = {0.f, 0.f, 0.f, 0.f};

    // ---- seed P = X1 = I + (dt/2)A (both views, hi/lo); load b, c ----
#pragma unroll
    for (int e = 0; e < 4; ++e) {
        int idx = t + e*NTH;
        int i = idx >> 6, j = idx & 63;
        float2 a = A2[idx];
        unsigned hb, lb;
        split2((i == j ? 1.0f : 0.0f) + hdt * a.x, hb, lb);
        XR[i*RS + j]       = (u16)(hb >> 16);
        XR[PSZ + i*RS + j] = (u16)(lb >> 16);
        XT[j*RS + i]       = (u16)(hb >> 16);
        XT[PSZ + j*RS + i] = (u16)(lb >> 16);
        split2(hdt * a.y, hb, lb);
        XR[2*PSZ + i*RS + j] = (u16)(hb >> 16);
        XR[3*PSZ + i*RS + j] = (u16)(lb >> 16);
        XT[2*PSZ + j*RS + i] = (u16)(hb >> 16);
        XT[3*PSZ + j*RS + i] = (u16)(lb >> 16);
    }
    if (t < NN) {
        float2 bv = ((const float2*)Bg)[h*NN + t];
        float2 cv = ((const float2*)Cg)[h*NN + t];
        bvr[t] = bv.x; bvi[t] = bv.y;
        unsigned hb, lb;
        split2(cv.x, hb, lb);                 // g_0 = c
        Gm[t]       = (u16)(hb >> 16);
        Gm[GSZ + t] = (u16)(lb >> 16);
        split2(cv.y, hb, lb);
        Gm[2*GSZ + t] = (u16)(hb >> 16);
        Gm[3*GSZ + t] = (u16)(lb >> 16);
    }
    __syncthreads();

    // ---- m1: Y = Ab*X1 (Ab from global, Bt = XT); paired; Y^T -> XF (b32 pairs) ----
    if (wv < 8) {
        float4_t P0 = z4, N0 = z4, I10 = z4, I20 = z4;
        float4_t P1 = z4, N1 = z4, I11 = z4, I21 = z4;
#pragma unroll
        for (int ks = 0; ks < 2; ++ks) {
            const int k0 = ks*32 + fq*8;
            unsigned vr[8], vi[8];
#pragma unroll
            for (int j = 0; j < 8; ++j) {
                float2 a = A2[parow*NN + k0 + j];
                vr[j] = __float_as_uint((parow == k0 + j ? 1.0f : 0.0f) - hdt * a.x);
                vi[j] = __float_as_uint(-hdt * a.y);
            }
            short8 Arh, Arl, Aih, Ail;
            frag_vals(vr, Arh, Arl);
            frag_vals(vi, Aih, Ail);
#pragma unroll
            for (int p = 0; p < 2; ++p) {
                const u16* bp = XT + (pb0 + p*16)*RS + k0;
                short8 Brh = *(const short8*)(bp);
                short8 Brl = *(const short8*)(bp + PSZ);
                short8 Bih = *(const short8*)(bp + 2*PSZ);
                short8 Bil = *(const short8*)(bp + 3*PSZ);
                float4_t &aP = p ? P1 : P0, &aN = p ? N1 : N0;
                float4_t &aI1 = p ? I11 : I10, &aI2 = p ? I21 : I20;
                aP = MFMA(Arh, Brh, aP); aP = MFMA(Arh, Brl, aP); aP = MFMA(Arl, Brh, aP);
                aN = MFMA(Aih, Bih, aN); aN = MFMA(Aih, Bil, aN); aN = MFMA(Ail, Bih, aN);
                aI1 = MFMA(Arh, Bih, aI1); aI1 = MFMA(Arh, Bil, aI1); aI1 = MFMA(Arl, Bih, aI1);
                aI2 = MFMA(Aih, Brh, aI2); aI2 = MFMA(Aih, Brl, aI2); aI2 = MFMA(Ail, Brh, aI2);
            }
        }
#pragma unroll
        for (int p = 0; p < 2; ++p) {
            const int bcol = pb0 + p*16;
            const float4_t &aP = p ? P1 : P0, &aN = p ? N1 : N0;
            const float4_t &aI1 = p ? I11 : I10, &aI2 = p ? I21 : I20;
#pragma unroll
            for (int rp = 0; rp < 2; ++rp) {   // Y^T contiguous rows -> packed b32 pairs
                int row0 = tip*16 + fq*4 + rp*2;
                unsigned h0, l0, h1, l1;
                split2(aP[rp*2]   - aN[rp*2],   h0, l0);
                split2(aP[rp*2+1] - aN[rp*2+1], h1, l1);
                *(unsigned*)&XF[bcol*RS + row0]       = __builtin_amdgcn_perm(h1, h0, PERM_HI);
                *(unsigned*)&XF[PSZ + bcol*RS + row0] = __builtin_amdgcn_perm(l1, l0, PERM_HI);
                split2(aI1[rp*2]   + aI2[rp*2],   h0, l0);
                split2(aI1[rp*2+1] + aI2[rp*2+1], h1, l1);
                *(unsigned*)&XF[2*PSZ + bcol*RS + row0] = __builtin_amdgcn_perm(h1, h0, PERM_HI);
                *(unsigned*)&XF[3*PSZ + bcol*RS + row0] = __builtin_amdgcn_perm(l1, l0, PERM_HI);
            }
        }
    }
    __syncthreads();

    // ---- m2: V = X1*Y (A = XR, Bt = U = XF); paired; V -> XR (row view only) ----
    {
        float4_t P0 = z4, N0 = z4, I10 = z4, I20 = z4;
        float4_t P1 = z4, N1 = z4, I11 = z4, I21 = z4;
        if (wv < 8)
            cmm_pair<PSZ, PSZ>(XR, XF, parow, pb0, fq, P0, N0, I10, I20, P1, N1, I11, I21);
        __syncthreads();   // all X1/Y reads done
        if (wv < 8) {
#pragma unroll
            for (int p = 0; p < 2; ++p) {
                const int bcol = pb0 + p*16;
                const float4_t &aP = p ? P1 : P0, &aN = p ? N1 : N0;
                const float4_t &aI1 = p ? I11 : I10, &aI2 = p ? I21 : I20;
#pragma unroll
                for (int r = 0; r < 4; ++r) {
                    int row = tip*16 + fq*4 + r;
                    unsigned hb, lb;
                    split2(aP[r] - aN[r], hb, lb);
                    XR[row*RS + bcol]       = (u16)(hb >> 16);
                    XR[PSZ + row*RS + bcol] = (u16)(lb >> 16);
                    split2(aI1[r] + aI2[r], hb, lb);
                    XR[2*PSZ + row*RS + bcol] = (u16)(hb >> 16);
                    XR[3*PSZ + row*RS + bcol] = (u16)(lb >> 16);
                }
            }
        }
    }
    __syncthreads();

    // ---- m3: P = dA = 2*(3X1 - 3V + V*Y) - I ; paired; write both views ----
    {
        float p_r[2][4], p_i[2][4];
        if (wv < 8) {
            float4_t P0 = z4, N0 = z4, I10 = z4, I20 = z4;
            float4_t P1 = z4, N1 = z4, I11 = z4, I21 = z4;
            cmm_pair<PSZ, PSZ>(XR, XF, parow, pb0, fq, P0, N0, I10, I20, P1, N1, I11, I21);
#pragma unroll
            for (int p = 0; p < 2; ++p) {
                const int bcol = pb0 + p*16;
                const float4_t &aP = p ? P1 : P0, &aN = p ? N1 : N0;
                const float4_t &aI1 = p ? I11 : I10, &aI2 = p ? I21 : I20;
#pragma unroll
                for (int r = 0; r < 4; ++r) {      // pre-barrier elementwise reads
                    int row = tip*16 + fq*4 + r;
                    float2 a = A2[row*NN + bcol];
                    float dd  = (row == bcol ? 1.0f : 0.0f);
                    float x1r = dd + hdt * a.x;
                    float x1i = hdt * a.y;
                    float vvr = ld2(XR, XR + PSZ, row*RS + bcol);
                    float vvi = ld2(XR + 2*PSZ, XR + 3*PSZ, row*RS + bcol);
                    p_r[p][r] = 2.0f*(3.0f*x1r - 3.0f*vvr + (aP[r] - aN[r])) - dd;
                    p_i[p][r] = 2.0f*(3.0f*x1i - 3.0f*vvi + (aI1[r] + aI2[r]));
                }
            }
        }
        __syncthreads();   // all V/Y reads done
        if (wv < 8) {
            store_P_vals(XR, XT, tip, pb0, fq, p_r[0], p_i[0]);
            store_P_vals(XR, XT, tip, pb1, fq, p_r[1], p_i[1]);
        }
    }
    __syncthreads();
    // P = dA (both views)

    // ---- u = dA*b (all 16 waves, 16 partials per row) ----
    {
        int n = t >> 4, part = t & 15;
        float ar = 0.f, ai = 0.f;
#pragma unroll
        for (int qq = 0; qq < 4; ++qq) {
            int k = part + 16*qq;
            float mr = ld2(XR, XR + PSZ, n*RS + k);
            float mi = ld2(XR + 2*PSZ, XR + 3*PSZ, n*RS + k);
            ar += mr*bvr[k] - mi*bvi[k];
            ai += mr*bvi[k] + mi*bvr[k];
        }
#pragma unroll
        for (int off = 8; off; off >>= 1) { ar += __shfl_xor(ar, off); ai += __shfl_xor(ai, off); }
        if (part == 0) { urr[n] = ar; uri[n] = ai; }
    }
    __syncthreads();

    // ---- ladder s = 1..9: riders (waves 8-15) CONCURRENT with 32x32 squaring (waves 0-3) ----
#pragma unroll 1
    for (int s = 1; s <= 9; ++s) {
        float16_t sP, sN, sI1, sI2;
        if (wv >= 8) {
            if (s == 1) {
                // x0 = h(u+b); x1 = h(dA u + u): 512 threads, 8 partials per row
                int n = (t >> 3) & 63, part = t & 7;
                float ar = 0.f, ai = 0.f;
#pragma unroll
                for (int qq = 0; qq < 8; ++qq) {
                    int k = part + 8*qq;
                    float mr = ld2(XR, XR + PSZ, n*RS + k);
                    float mi = ld2(XR + 2*PSZ, XR + 3*PSZ, n*RS + k);
                    ar += mr*urr[k] - mi*uri[k];
                    ai += mr*uri[k] + mi*urr[k];
                }
#pragma unroll
                for (int off = 4; off; off >>= 1) { ar += __shfl_xor(ar, off); ai += __shfl_xor(ai, off); }
                if (part == 0) {
                    float u_r = urr[n], u_i = uri[n];
                    unsigned hb, lb;
                    split2(hdt*(u_r + bvr[n]), hb, lb);
                    XF[n]       = (u16)(hb >> 16); XF[PSZ + n]       = (u16)(lb >> 16);
                    split2(hdt*(u_i + bvi[n]), hb, lb);
                    XF[2*PSZ + n] = (u16)(hb >> 16); XF[3*PSZ + n]   = (u16)(lb >> 16);
                    split2(hdt*(ar + u_r), hb, lb);
                    XF[RS + n]       = (u16)(hb >> 16); XF[PSZ + RS + n]   = (u16)(lb >> 16);
                    split2(hdt*(ai + u_i), hb, lb);
                    XF[2*PSZ + RS + n] = (u16)(hb >> 16); XF[3*PSZ + RS + n] = (u16)(lb >> 16);
                }
            } else if (s <= 6) {
                const int C = 1 << (s-1);
                const int w = wv - 8;
                const int nT = (s == 6) ? 8 : 4;
                if (w < nT) {
                    const int rt = w >> 2, ct = w & 3;
                    float4_t aP = z4, aN = z4, aI1 = z4, aI2 = z4;
                    cmm_tile<PSZ, PSZ, true>(XF, XR, rt*16 + fm, ct*16 + fm, fq, aP, aN, aI1, aI2);
#pragma unroll
                    for (int r = 0; r < 4; ++r) {
                        int orow = C + rt*16 + fq*4 + r;
                        int oc   = ct*16 + fm;
                        unsigned hb, lb;
                        split2(aP[r] - aN[r], hb, lb);
                        XF[orow*RS + oc]       = (u16)(hb >> 16);
                        XF[PSZ + orow*RS + oc] = (u16)(lb >> 16);
                        split2(aI1[r] + aI2[r], hb, lb);
                        XF[2*PSZ + orow*RS + oc] = (u16)(hb >> 16);
                        XF[3*PSZ + orow*RS + oc] = (u16)(lb >> 16);
                    }
                }
            } else {
                const int C = 1 << (s-7);     // 1,2,4
                const int w = wv - 8;
                if (w < 4) {
                    float4_t aP = z4, aN = z4, aI1 = z4, aI2 = z4;
                    cmm_tile<GSZ, PSZ, true>(Gm, XT, fm, w*16 + fm, fq, aP, aN, aI1, aI2);
#pragma unroll
                    for (int r = 0; r < 4; ++r) {
                        int orow = C + fq*4 + r;   // <= 19 < 32, no mask
                        int oc   = w*16 + fm;
                        unsigned hb, lb;
                        split2(aP[r] - aN[r], hb, lb);
                        Gm[orow*RS + oc]       = (u16)(hb >> 16);
                        Gm[GSZ + orow*RS + oc] = (u16)(lb >> 16);
                        split2(aI1[r] + aI2[r], hb, lb);
                        Gm[2*GSZ + orow*RS + oc] = (u16)(hb >> 16);
                        Gm[3*GSZ + orow*RS + oc] = (u16)(lb >> 16);
                    }
                }
            }
        } else if (wv < 4) {
            // squaring (waves 0-3, 32x32 tiles): P <- P*P
#pragma unroll
            for (int g = 0; g < 16; ++g) { sP[g] = 0.f; sN[g] = 0.f; sI1[g] = 0.f; sI2[g] = 0.f; }
            cmm32_tile<PSZ, PSZ>(XR, XT, arow32, bcol32, khalf, sP, sN, sI1, sI2);
        }
        __syncthreads();   // all P reads (riders + frags) complete
        if (wv < 4) {
            float16_t pR, pI;
#pragma unroll
            for (int g = 0; g < 16; ++g) { pR[g] = sP[g] - sN[g]; pI[g] = sI1[g] + sI2[g]; }
            store_P_vals32(XR, XT, ti2*32, tj2*32, lane, pR, pI);
        }
        __syncthreads();
    }
    // P = dA^512 ; XF rows 0..63 = x_i ; Gm rows 0..7 = g_0..g_7

    // ---- tail tt = 0..3: chained dA^512 G-steps + K tiles (direct global) ----
    // G rows [8+8tt, 24+8tt) <- A rows [8tt, 8tt+16) (out row 8+ab+m depends
    // only on A row ab+m, so in-interval row overlap is benign).
#pragma unroll 1
    for (int tt = 0; tt < 4; ++tt) {
        if (tt < 3 && wv < 4) {
            const int ab = tt * 8;
            float4_t aP = z4, aN = z4, aI1 = z4, aI2 = z4;
            cmm_tile<GSZ, PSZ, true>(Gm, XT, ab + fm, wv*16 + fm, fq, aP, aN, aI1, aI2);
#pragma unroll
            for (int r = 0; r < 4; ++r) {
                int orow = 8 + ab + fq*4 + r;
                if (orow < 32) {
                    int oc = wv*16 + fm;
                    unsigned hb, lb;
                    split2(aP[r] - aN[r], hb, lb);
                    Gm[orow*RS + oc]       = (u16)(hb >> 16);
                    Gm[GSZ + orow*RS + oc] = (u16)(lb >> 16);
                    split2(aI1[r] + aI2[r], hb, lb);
                    Gm[2*GSZ + orow*RS + oc] = (u16)(hb >> 16);
                    Gm[3*GSZ + orow*RS + oc] = (u16)(lb >> 16);
                }
            }
        }
        if (wv >= 4 && wv < 8) {           // K rows [8tt, 8tt+8): direct global store
            const int jb = tt * 8;
            // clamp A row inside Gm's 32 rows (rows >= 32 feed only discarded C rows)
            int ga = jb + fm; if (ga > 31) ga = 31;
            float4_t aP = z4, aN = z4, aI1 = z4, aI2 = z4;
            cmm_tile<GSZ, PSZ, false>(Gm, XF, ga, (wv-4)*16 + fm, fq, aP, aN, aI1, aI2);
            if (fq < 2) {
                size_t base = (size_t)h * LSEQ;
#pragma unroll
                for (int r = 0; r < 4; ++r)
                    outp[base + (jb + fq*4 + r)*NN + (wv-4)*16 + fm] = aP[r] - aN[r];
            }
        }
        if (tt < 3) __syncthreads();
    }
}

extern "C" void kernel_launch(void* const* d_in, const int* in_sizes, int n_in,
                              void* d_out, int out_size, void* d_ws, size_t ws_size,
                              hipStream_t stream) {
    const float* A  = (const float*)d_in[0];
    const float* B  = (const float*)d_in[1];
    const float* C  = (const float*)d_in[2];
    const float* ld = (const float*)d_in[3];
    float* out = (float*)d_out;
    ssm_kernel<<<dim3(NH), dim3(NTH), 0, stream>>>(A, B, C, ld, out);
}

// Round 5
// 95.163 us; speedup vs baseline: 1.1223x; 1.1223x over previous
//
#include <hip/hip_runtime.h>
#include <math.h>

// Problem constants (fixed by reference: H=256, N=64, CH=1, L=2048)
#define NH   256
#define NN   64
#define LSEQ 2048
#define RS   72       // LDS row stride in bf16 elements (144 B: 16B-aligned rows)
#define PSZ  4608     // elems per 64-row component array (64*72), 9216 B
#define GSZ  2304     // elems per 32-row component array (32*72), 4608 B
#define NTH  1024

typedef __attribute__((ext_vector_type(8))) short short8;     // 8 bf16 (MFMA A/B frag)
typedef __attribute__((ext_vector_type(4))) float float4_t;   // 16x16 MFMA C/D frag
typedef __attribute__((ext_vector_type(16))) float float16_t; // 32x32 MFMA C/D frag
typedef unsigned short u16;

#define MFMA(a,b,c)   __builtin_amdgcn_mfma_f32_16x16x32_bf16((a),(b),(c),0,0,0)
#define MFMA32(a,b,c) __builtin_amdgcn_mfma_f32_32x32x16_bf16((a),(b),(c),0,0,0)
#define PERM_HI 0x07060302u   // [a.hi16 | b.hi16]

// value v -> hi bits (bf16<<16) and lo bits (f32 of v-hi; its top16 = lo bf16)
static __device__ __forceinline__ void split2(float v, unsigned& hb, unsigned& lb) {
    hb = __float_as_uint(v) & 0xffff0000u;
    lb = __float_as_uint(v - __uint_as_float(hb));
}
// reconstruct f32 from separated hi/lo bf16 arrays
static __device__ __forceinline__ float ld2(const u16* hp, const u16* lp, int idx) {
    return __uint_as_float((unsigned)hp[idx] << 16)
         + __uint_as_float((unsigned)lp[idx] << 16);
}
static __device__ __forceinline__ short8 neg8(short8 v) {
    union { short8 s; int i[4]; } u; u.s = v;
#pragma unroll
    for (int m = 0; m < 4; ++m) u.i[m] ^= 0x80008000;
    return u.s;
}

// build hi/lo short8 frags from 8 f32 bit patterns (m1 global path only)
static __device__ __forceinline__ void frag_vals(const unsigned* e, short8& hi, short8& lo) {
    unsigned lb[8];
#pragma unroll
    for (int m = 0; m < 8; ++m) {
        unsigned hv = e[m] & 0xffff0000u;
        lb[m] = __float_as_uint(__uint_as_float(e[m]) - __uint_as_float(hv));
    }
    union { short8 s; unsigned u[4]; } H, L;
#pragma unroll
    for (int m = 0; m < 4; ++m) {
        H.u[m] = __builtin_amdgcn_perm(e[2*m+1],  e[2*m],  PERM_HI);
        L.u[m] = __builtin_amdgcn_perm(lb[2*m+1], lb[2*m], PERM_HI);
    }
    hi = H.s; lo = L.s;
}

// One 16x16 tile of complex P = A*B, K=64. A and B-transpose are separated
// hi/lo bf16 component arrays: [rh | rl | ih | il] each ASZ/BSZ elems apart.
template<int ASZ, int BSZ, bool IMAG>
static __device__ __forceinline__ void cmm_tile(
    const u16* __restrict__ Ab, const u16* __restrict__ Bb,
    int arow, int bcol, int fq,
    float4_t& accP, float4_t& accN, float4_t& accI1, float4_t& accI2)
{
#pragma unroll
    for (int ks = 0; ks < 2; ++ks) {
        const int k0 = ks*32 + fq*8;
        const u16* ap = Ab + arow*RS + k0;
        const u16* bp = Bb + bcol*RS + k0;
        short8 Arh = *(const short8*)(ap);
        short8 Arl = *(const short8*)(ap + ASZ);
        short8 Aih = *(const short8*)(ap + 2*ASZ);
        short8 Ail = *(const short8*)(ap + 3*ASZ);
        short8 Brh = *(const short8*)(bp);
        short8 Brl = *(const short8*)(bp + BSZ);
        short8 Bih = *(const short8*)(bp + 2*BSZ);
        short8 Bil = *(const short8*)(bp + 3*BSZ);
        accP = MFMA(Arh, Brh, accP); accP = MFMA(Arh, Brl, accP); accP = MFMA(Arl, Brh, accP);
        accN = MFMA(Aih, Bih, accN); accN = MFMA(Aih, Bil, accN); accN = MFMA(Ail, Bih, accN);
        if (IMAG) {
            accI1 = MFMA(Arh, Bih, accI1); accI1 = MFMA(Arh, Bil, accI1); accI1 = MFMA(Arl, Bih, accI1);
            accI2 = MFMA(Aih, Brh, accI2); accI2 = MFMA(Aih, Brl, accI2); accI2 = MFMA(Ail, Brh, accI2);
        }
    }
}

// Paired tiles: one A-row panel (arow), two B cols (bcol0, bcol0+16).
template<int ASZ, int BSZ>
static __device__ __forceinline__ void cmm_pair(
    const u16* __restrict__ Ab, const u16* __restrict__ Bb,
    int arow, int bcol0, int fq,
    float4_t& P0, float4_t& N0, float4_t& I10, float4_t& I20,
    float4_t& P1, float4_t& N1, float4_t& I11, float4_t& I21)
{
#pragma unroll
    for (int ks = 0; ks < 2; ++ks) {
        const int k0 = ks*32 + fq*8;
        const u16* ap = Ab + arow*RS + k0;
        short8 Arh = *(const short8*)(ap);
        short8 Arl = *(const short8*)(ap + ASZ);
        short8 Aih = *(const short8*)(ap + 2*ASZ);
        short8 Ail = *(const short8*)(ap + 3*ASZ);
        {
            const u16* bp0 = Bb + bcol0*RS + k0;
            short8 Brh = *(const short8*)(bp0);
            short8 Brl = *(const short8*)(bp0 + BSZ);
            short8 Bih = *(const short8*)(bp0 + 2*BSZ);
            short8 Bil = *(const short8*)(bp0 + 3*BSZ);
            P0 = MFMA(Arh, Brh, P0); P0 = MFMA(Arh, Brl, P0); P0 = MFMA(Arl, Brh, P0);
            N0 = MFMA(Aih, Bih, N0); N0 = MFMA(Aih, Bil, N0); N0 = MFMA(Ail, Bih, N0);
            I10 = MFMA(Arh, Bih, I10); I10 = MFMA(Arh, Bil, I10); I10 = MFMA(Arl, Bih, I10);
            I20 = MFMA(Aih, Brh, I20); I20 = MFMA(Aih, Brl, I20); I20 = MFMA(Ail, Brh, I20);
        }
        {
            const u16* bp1 = Bb + (bcol0 + 16)*RS + k0;
            short8 Brh = *(const short8*)(bp1);
            short8 Brl = *(const short8*)(bp1 + BSZ);
            short8 Bih = *(const short8*)(bp1 + 2*BSZ);
            short8 Bil = *(const short8*)(bp1 + 3*BSZ);
            P1 = MFMA(Arh, Brh, P1); P1 = MFMA(Arh, Brl, P1); P1 = MFMA(Arl, Brh, P1);
            N1 = MFMA(Aih, Bih, N1); N1 = MFMA(Aih, Bil, N1); N1 = MFMA(Ail, Bih, N1);
            I11 = MFMA(Arh, Bih, I11); I11 = MFMA(Arh, Bil, I11); I11 = MFMA(Arl, Bih, I11);
            I21 = MFMA(Aih, Brh, I21); I21 = MFMA(Aih, Brl, I21); I21 = MFMA(Ail, Brh, I21);
        }
    }
}

// 32x32 complex tile, K=64, via mfma_f32_32x32x16_bf16 (4 k-steps).
// TWO chains only (R, I): imag*imag folded in via negated Aih/Ail frags
// (8 v_xor per k-step). 32 acc VGPRs live across the barrier -> no spill
// under the 128-VGPR cap (round-4 post-mortem: 4-chain/64-reg spilled).
template<int ASZ, int BSZ>
static __device__ __forceinline__ void cmm32_tile2(
    const u16* __restrict__ Ab, const u16* __restrict__ Bb,
    int arow, int bcol, int khalf,
    float16_t& R, float16_t& I)
{
#pragma unroll
    for (int ks = 0; ks < 4; ++ks) {
        const int k0 = ks*16 + khalf;
        const u16* ap = Ab + arow*RS + k0;
        const u16* bp = Bb + bcol*RS + k0;
        short8 Arh = *(const short8*)(ap);
        short8 Arl = *(const short8*)(ap + ASZ);
        short8 Aih = *(const short8*)(ap + 2*ASZ);
        short8 Ail = *(const short8*)(ap + 3*ASZ);
        short8 Brh = *(const short8*)(bp);
        short8 Brl = *(const short8*)(bp + BSZ);
        short8 Bih = *(const short8*)(bp + 2*BSZ);
        short8 Bil = *(const short8*)(bp + 3*BSZ);
        short8 nAih = neg8(Aih), nAil = neg8(Ail);
        R = MFMA32(Arh, Brh, R);  I = MFMA32(Arh, Bih, I);
        R = MFMA32(Arh, Brl, R);  I = MFMA32(Arh, Bil, I);
        R = MFMA32(Arl, Brh, R);  I = MFMA32(Arl, Bih, I);
        R = MFMA32(nAih, Bih, R); I = MFMA32(Aih, Brh, I);
        R = MFMA32(nAih, Bil, R); I = MFMA32(Aih, Brl, I);
        R = MFMA32(nAil, Bih, R); I = MFMA32(Ail, Brh, I);
    }
}

// store complex values p_r/p_i (16x16 C-frag rows) into BOTH P views.
static __device__ __forceinline__ void store_P_vals(
    u16* XR, u16* XT, int ti, int bcol, int fq,
    const float* p_r, const float* p_i)
{
    unsigned hR[4], lR[4], hI[4], lI[4];
#pragma unroll
    for (int r = 0; r < 4; ++r) {
        split2(p_r[r], hR[r], lR[r]);
        split2(p_i[r], hI[r], lI[r]);
        int row = ti*16 + fq*4 + r;
        XR[row*RS + bcol]         = (u16)(hR[r] >> 16);
        XR[PSZ + row*RS + bcol]   = (u16)(lR[r] >> 16);
        XR[2*PSZ + row*RS + bcol] = (u16)(hI[r] >> 16);
        XR[3*PSZ + row*RS + bcol] = (u16)(lI[r] >> 16);
    }
    int tb = bcol*RS + ti*16 + fq*4;
    uint2 w;
    w.x = __builtin_amdgcn_perm(hR[1], hR[0], PERM_HI);
    w.y = __builtin_amdgcn_perm(hR[3], hR[2], PERM_HI);
    *(uint2*)&XT[tb] = w;
    w.x = __builtin_amdgcn_perm(lR[1], lR[0], PERM_HI);
    w.y = __builtin_amdgcn_perm(lR[3], lR[2], PERM_HI);
    *(uint2*)&XT[PSZ + tb] = w;
    w.x = __builtin_amdgcn_perm(hI[1], hI[0], PERM_HI);
    w.y = __builtin_amdgcn_perm(hI[3], hI[2], PERM_HI);
    *(uint2*)&XT[2*PSZ + tb] = w;
    w.x = __builtin_amdgcn_perm(lI[1], lI[0], PERM_HI);
    w.y = __builtin_amdgcn_perm(lI[3], lI[2], PERM_HI);
    *(uint2*)&XT[3*PSZ + tb] = w;
}

// store 32x32 C-frag (16 regs: col=lane&31, row=(g&3)+8*(g>>2)+4*(lane>>5))
// into BOTH views. XR: scalar b16; XT: 4 consecutive rows per reg-quad -> b64.
static __device__ __forceinline__ void store_P_vals32(
    u16* XR, u16* XT, int trow, int tcol, int lane,
    const float16_t& vR, const float16_t& vI)
{
    const int col = tcol + (lane & 31);
    const int hi4 = (lane >> 5) * 4;
#pragma unroll
    for (int q = 0; q < 4; ++q) {
        unsigned hR[4], lR[4], hI[4], lI[4];
#pragma unroll
        for (int rr = 0; rr < 4; ++rr) {
            const int g = 4*q + rr;
            split2(vR[g], hR[rr], lR[rr]);
            split2(vI[g], hI[rr], lI[rr]);
            const int row = trow + rr + 8*q + hi4;
            XR[row*RS + col]         = (u16)(hR[rr] >> 16);
            XR[PSZ + row*RS + col]   = (u16)(lR[rr] >> 16);
            XR[2*PSZ + row*RS + col] = (u16)(hI[rr] >> 16);
            XR[3*PSZ + row*RS + col] = (u16)(lI[rr] >> 16);
        }
        const int tb = col*RS + trow + 8*q + hi4;   // 8B-aligned
        uint2 w;
        w.x = __builtin_amdgcn_perm(hR[1], hR[0], PERM_HI);
        w.y = __builtin_amdgcn_perm(hR[3], hR[2], PERM_HI);
        *(uint2*)&XT[tb] = w;
        w.x = __builtin_amdgcn_perm(lR[1], lR[0], PERM_HI);
        w.y = __builtin_amdgcn_perm(lR[3], lR[2], PERM_HI);
        *(uint2*)&XT[PSZ + tb] = w;
        w.x = __builtin_amdgcn_perm(hI[1], hI[0], PERM_HI);
        w.y = __builtin_amdgcn_perm(hI[3], hI[2], PERM_HI);
        *(uint2*)&XT[2*PSZ + tb] = w;
        w.x = __builtin_amdgcn_perm(lI[1], lI[0], PERM_HI);
        w.y = __builtin_amdgcn_perm(lI[3], lI[2], PERM_HI);
        *(uint2*)&XT[3*PSZ + tb] = w;
    }
}

// k[h, 64j+i] = Re( g_j . x_i ),  g_j = c^T (dA^64)^j,  x_i = dA^i dB
// Cubic Newton: X1 = I + (dt/2)A; Y = Ab*X1; V = X1*Y; X2 = 3X1 - 3V + VY.
// P = dA = 2*X2 - I folded into m3 epilogue.
// dB = dt/2 (dA b + b): u = dA*b, then x0 = dt/2(u+b), x1 = dt/2(dA u + u).
// Ladder: 9 squarings to dA^512 on waves 0-3 (32x32 MFMA, 2-chain, no spill);
// riders run CONCURRENTLY on waves 8-15: X-rounds C=2..32 at s=2..6,
// G-rounds C=1,2,4 at s=7..9; tail: 3 chained dA^512 G-steps + K tiles.
__global__ __launch_bounds__(NTH, 4) void ssm_kernel(
    const float* __restrict__ Ag,
    const float* __restrict__ Bg,
    const float* __restrict__ Cg,
    const float* __restrict__ LogDt,
    float* __restrict__ outp)
{
    __shared__ __align__(16) unsigned char lds[130048];
    u16* XR = (u16*)(lds);            // P row-major: rh,rl,ih,il (4 x 9216 B)
    u16* XT = (u16*)(lds +  36864);   // P transposed: rh,rl,ih,il
    u16* XF = (u16*)(lds +  73728);   // Xf[v][q] = x_v[q]; aliased as U = Y^T in Newton
    u16* Gm = (u16*)(lds + 110592);   // G[j][q] = g_j[q], 32 rows (4 x 4608 B)
    float* bvr = (float*)(lds + 129024);
    float* bvi = (float*)(lds + 129280);
    float* urr = (float*)(lds + 129536);   // u = dA*b scratch
    float* uri = (float*)(lds + 129792);

    const int t    = threadIdx.x;
    const int lane = t & 63;
    const int wv   = t >> 6;                 // 0..15
    const int fm   = lane & 15, fq = lane >> 4;
    const int h    = blockIdx.x;

    // paired-tile mapping (waves 0-7): row band tip, col halves tjp*32 + {0,16}
    const int tip  = wv >> 1, tjp = wv & 1;
    const int parow = tip*16 + fm;
    const int pb0   = tjp*32 + fm;
    const int pb1   = pb0 + 16;

    // 32x32 squaring mapping (waves 0-3): tile (ti2, tj2)
    const int ti2 = (wv >> 1) & 1, tj2 = wv & 1;
    const int arow32 = ti2*32 + (lane & 31);
    const int bcol32 = tj2*32 + (lane & 31);
    const int khalf  = (lane >> 5) * 8;

    const float dt  = expf(LogDt[h]);
    const float hdt = 0.5f * dt;

    const float2* A2 = (const float2*)(Ag + (size_t)h * NN * NN * 2);
    const float4_t z4 = {0.f, 0.f, 0.f, 0.f};

    // ---- seed P = X1 = I + (dt/2)A (both views, hi/lo); load b, c ----
#pragma unroll
    for (int e = 0; e < 4; ++e) {
        int idx = t + e*NTH;
        int i = idx >> 6, j = idx & 63;
        float2 a = A2[idx];
        unsigned hb, lb;
        split2((i == j ? 1.0f : 0.0f) + hdt * a.x, hb, lb);
        XR[i*RS + j]       = (u16)(hb >> 16);
        XR[PSZ + i*RS + j] = (u16)(lb >> 16);
        XT[j*RS + i]       = (u16)(hb >> 16);
        XT[PSZ + j*RS + i] = (u16)(lb >> 16);
        split2(hdt * a.y, hb, lb);
        XR[2*PSZ + i*RS + j] = (u16)(hb >> 16);
        XR[3*PSZ + i*RS + j] = (u16)(lb >> 16);
        XT[2*PSZ + j*RS + i] = (u16)(hb >> 16);
        XT[3*PSZ + j*RS + i] = (u16)(lb >> 16);
    }
    if (t < NN) {
        float2 bv = ((const float2*)Bg)[h*NN + t];
        float2 cv = ((const float2*)Cg)[h*NN + t];
        bvr[t] = bv.x; bvi[t] = bv.y;
        unsigned hb, lb;
        split2(cv.x, hb, lb);                 // g_0 = c
        Gm[t]       = (u16)(hb >> 16);
        Gm[GSZ + t] = (u16)(lb >> 16);
        split2(cv.y, hb, lb);
        Gm[2*GSZ + t] = (u16)(hb >> 16);
        Gm[3*GSZ + t] = (u16)(lb >> 16);
    }
    __syncthreads();

    // ---- m1: Y = Ab*X1 (Ab from global, Bt = XT); paired; Y^T -> XF (b32 pairs) ----
    if (wv < 8) {
        float4_t P0 = z4, N0 = z4, I10 = z4, I20 = z4;
        float4_t P1 = z4, N1 = z4, I11 = z4, I21 = z4;
#pragma unroll
        for (int ks = 0; ks < 2; ++ks) {
            const int k0 = ks*32 + fq*8;
            unsigned vr[8], vi[8];
#pragma unroll
            for (int j = 0; j < 8; ++j) {
                float2 a = A2[parow*NN + k0 + j];
                vr[j] = __float_as_uint((parow == k0 + j ? 1.0f : 0.0f) - hdt * a.x);
                vi[j] = __float_as_uint(-hdt * a.y);
            }
            short8 Arh, Arl, Aih, Ail;
            frag_vals(vr, Arh, Arl);
            frag_vals(vi, Aih, Ail);
#pragma unroll
            for (int p = 0; p < 2; ++p) {
                const u16* bp = XT + (pb0 + p*16)*RS + k0;
                short8 Brh = *(const short8*)(bp);
                short8 Brl = *(const short8*)(bp + PSZ);
                short8 Bih = *(const short8*)(bp + 2*PSZ);
                short8 Bil = *(const short8*)(bp + 3*PSZ);
                float4_t &aP = p ? P1 : P0, &aN = p ? N1 : N0;
                float4_t &aI1 = p ? I11 : I10, &aI2 = p ? I21 : I20;
                aP = MFMA(Arh, Brh, aP); aP = MFMA(Arh, Brl, aP); aP = MFMA(Arl, Brh, aP);
                aN = MFMA(Aih, Bih, aN); aN = MFMA(Aih, Bil, aN); aN = MFMA(Ail, Bih, aN);
                aI1 = MFMA(Arh, Bih, aI1); aI1 = MFMA(Arh, Bil, aI1); aI1 = MFMA(Arl, Bih, aI1);
                aI2 = MFMA(Aih, Brh, aI2); aI2 = MFMA(Aih, Brl, aI2); aI2 = MFMA(Ail, Brh, aI2);
            }
        }
#pragma unroll
        for (int p = 0; p < 2; ++p) {
            const int bcol = pb0 + p*16;
            const float4_t &aP = p ? P1 : P0, &aN = p ? N1 : N0;
            const float4_t &aI1 = p ? I11 : I10, &aI2 = p ? I21 : I20;
#pragma unroll
            for (int rp = 0; rp < 2; ++rp) {   // Y^T contiguous rows -> packed b32 pairs
                int row0 = tip*16 + fq*4 + rp*2;
                unsigned h0, l0, h1, l1;
                split2(aP[rp*2]   - aN[rp*2],   h0, l0);
                split2(aP[rp*2+1] - aN[rp*2+1], h1, l1);
                *(unsigned*)&XF[bcol*RS + row0]       = __builtin_amdgcn_perm(h1, h0, PERM_HI);
                *(unsigned*)&XF[PSZ + bcol*RS + row0] = __builtin_amdgcn_perm(l1, l0, PERM_HI);
                split2(aI1[rp*2]   + aI2[rp*2],   h0, l0);
                split2(aI1[rp*2+1] + aI2[rp*2+1], h1, l1);
                *(unsigned*)&XF[2*PSZ + bcol*RS + row0] = __builtin_amdgcn_perm(h1, h0, PERM_HI);
                *(unsigned*)&XF[3*PSZ + bcol*RS + row0] = __builtin_amdgcn_perm(l1, l0, PERM_HI);
            }
        }
    }
    __syncthreads();

    // ---- m2: V = X1*Y (A = XR, Bt = U = XF); paired; V -> XR (row view only) ----
    {
        float4_t P0 = z4, N0 = z4, I10 = z4, I20 = z4;
        float4_t P1 = z4, N1 = z4, I11 = z4, I21 = z4;
        if (wv < 8)
            cmm_pair<PSZ, PSZ>(XR, XF, parow, pb0, fq, P0, N0, I10, I20, P1, N1, I11, I21);
        __syncthreads();   // all X1/Y reads done
        if (wv < 8) {
#pragma unroll
            for (int p = 0; p < 2; ++p) {
                const int bcol = pb0 + p*16;
                const float4_t &aP = p ? P1 : P0, &aN = p ? N1 : N0;
                const float4_t &aI1 = p ? I11 : I10, &aI2 = p ? I21 : I20;
#pragma unroll
                for (int r = 0; r < 4; ++r) {
                    int row = tip*16 + fq*4 + r;
                    unsigned hb, lb;
                    split2(aP[r] - aN[r], hb, lb);
                    XR[row*RS + bcol]       = (u16)(hb >> 16);
                    XR[PSZ + row*RS + bcol] = (u16)(lb >> 16);
                    split2(aI1[r] + aI2[r], hb, lb);
                    XR[2*PSZ + row*RS + bcol] = (u16)(hb >> 16);
                    XR[3*PSZ + row*RS + bcol] = (u16)(lb >> 16);
                }
            }
        }
    }
    __syncthreads();

    // ---- m3: P = dA = 2*(3X1 - 3V + V*Y) - I ; paired; write both views ----
    {
        float p_r[2][4], p_i[2][4];
        if (wv < 8) {
            float4_t P0 = z4, N0 = z4, I10 = z4, I20 = z4;
            float4_t P1 = z4, N1 = z4, I11 = z4, I21 = z4;
            cmm_pair<PSZ, PSZ>(XR, XF, parow, pb0, fq, P0, N0, I10, I20, P1, N1, I11, I21);
#pragma unroll
            for (int p = 0; p < 2; ++p) {
                const int bcol = pb0 + p*16;
                const float4_t &aP = p ? P1 : P0, &aN = p ? N1 : N0;
                const float4_t &aI1 = p ? I11 : I10, &aI2 = p ? I21 : I20;
#pragma unroll
                for (int r = 0; r < 4; ++r) {      // pre-barrier elementwise reads
                    int row = tip*16 + fq*4 + r;
                    float2 a = A2[row*NN + bcol];
                    float dd  = (row == bcol ? 1.0f : 0.0f);
                    float x1r = dd + hdt * a.x;
                    float x1i = hdt * a.y;
                    float vvr = ld2(XR, XR + PSZ, row*RS + bcol);
                    float vvi = ld2(XR + 2*PSZ, XR + 3*PSZ, row*RS + bcol);
                    p_r[p][r] = 2.0f*(3.0f*x1r - 3.0f*vvr + (aP[r] - aN[r])) - dd;
                    p_i[p][r] = 2.0f*(3.0f*x1i - 3.0f*vvi + (aI1[r] + aI2[r]));
                }
            }
        }
        __syncthreads();   // all V/Y reads done
        if (wv < 8) {
            store_P_vals(XR, XT, tip, pb0, fq, p_r[0], p_i[0]);
            store_P_vals(XR, XT, tip, pb1, fq, p_r[1], p_i[1]);
        }
    }
    __syncthreads();
    // P = dA (both views)

    // ---- u = dA*b (all 16 waves, 16 partials per row) ----
    {
        int n = t >> 4, part = t & 15;
        float ar = 0.f, ai = 0.f;
#pragma unroll
        for (int qq = 0; qq < 4; ++qq) {
            int k = part + 16*qq;
            float mr = ld2(XR, XR + PSZ, n*RS + k);
            float mi = ld2(XR + 2*PSZ, XR + 3*PSZ, n*RS + k);
            ar += mr*bvr[k] - mi*bvi[k];
            ai += mr*bvi[k] + mi*bvr[k];
        }
#pragma unroll
        for (int off = 8; off; off >>= 1) { ar += __shfl_xor(ar, off); ai += __shfl_xor(ai, off); }
        if (part == 0) { urr[n] = ar; uri[n] = ai; }
    }
    __syncthreads();

    // ---- ladder s = 1..9: riders (waves 8-15) CONCURRENT with 32x32 squaring (waves 0-3) ----
#pragma unroll 1
    for (int s = 1; s <= 9; ++s) {
        float16_t sR, sI;
        if (wv >= 8) {
            if (s == 1) {
                // x0 = h(u+b); x1 = h(dA u + u): 512 threads, 8 partials per row
                int n = (t >> 3) & 63, part = t & 7;
                float ar = 0.f, ai = 0.f;
#pragma unroll
                for (int qq = 0; qq < 8; ++qq) {
                    int k = part + 8*qq;
                    float mr = ld2(XR, XR + PSZ, n*RS + k);
                    float mi = ld2(XR + 2*PSZ, XR + 3*PSZ, n*RS + k);
                    ar += mr*urr[k] - mi*uri[k];
                    ai += mr*uri[k] + mi*urr[k];
                }
#pragma unroll
                for (int off = 4; off; off >>= 1) { ar += __shfl_xor(ar, off); ai += __shfl_xor(ai, off); }
                if (part == 0) {
                    float u_r = urr[n], u_i = uri[n];
                    unsigned hb, lb;
                    split2(hdt*(u_r + bvr[n]), hb, lb);
                    XF[n]       = (u16)(hb >> 16); XF[PSZ + n]       = (u16)(lb >> 16);
                    split2(hdt*(u_i + bvi[n]), hb, lb);
                    XF[2*PSZ + n] = (u16)(hb >> 16); XF[3*PSZ + n]   = (u16)(lb >> 16);
                    split2(hdt*(ar + u_r), hb, lb);
                    XF[RS + n]       = (u16)(hb >> 16); XF[PSZ + RS + n]   = (u16)(lb >> 16);
                    split2(hdt*(ai + u_i), hb, lb);
                    XF[2*PSZ + RS + n] = (u16)(hb >> 16); XF[3*PSZ + RS + n] = (u16)(lb >> 16);
                }
            } else if (s <= 6) {
                const int C = 1 << (s-1);
                const int w = wv - 8;
                const int nT = (s == 6) ? 8 : 4;
                if (w < nT) {
                    const int rt = w >> 2, ct = w & 3;
                    float4_t aP = z4, aN = z4, aI1 = z4, aI2 = z4;
                    cmm_tile<PSZ, PSZ, true>(XF, XR, rt*16 + fm, ct*16 + fm, fq, aP, aN, aI1, aI2);
#pragma unroll
                    for (int r = 0; r < 4; ++r) {
                        int orow = C + rt*16 + fq*4 + r;
                        int oc   = ct*16 + fm;
                        unsigned hb, lb;
                        split2(aP[r] - aN[r], hb, lb);
                        XF[orow*RS + oc]       = (u16)(hb >> 16);
                        XF[PSZ + orow*RS + oc] = (u16)(lb >> 16);
                        split2(aI1[r] + aI2[r], hb, lb);
                        XF[2*PSZ + orow*RS + oc] = (u16)(hb >> 16);
                        XF[3*PSZ + orow*RS + oc] = (u16)(lb >> 16);
                    }
                }
            } else {
                const int C = 1 << (s-7);     // 1,2,4
                const int w = wv - 8;
                if (w < 4) {
                    float4_t aP = z4, aN = z4, aI1 = z4, aI2 = z4;
                    cmm_tile<GSZ, PSZ, true>(Gm, XT, fm, w*16 + fm, fq, aP, aN, aI1, aI2);
#pragma unroll
                    for (int r = 0; r < 4; ++r) {
                        int orow = C + fq*4 + r;   // <= 19 < 32, no mask
                        int oc   = w*16 + fm;
                        unsigned hb, lb;
                        split2(aP[r] - aN[r], hb, lb);
                        Gm[orow*RS + oc]       = (u16)(hb >> 16);
                        Gm[GSZ + orow*RS + oc] = (u16)(lb >> 16);
                        split2(aI1[r] + aI2[r], hb, lb);
                        Gm[2*GSZ + orow*RS + oc] = (u16)(hb >> 16);
                        Gm[3*GSZ + orow*RS + oc] = (u16)(lb >> 16);
                    }
                }
            }
        } else if (wv < 4) {
            // squaring (waves 0-3, 32x32 tiles, 2-chain): P <- P*P
#pragma unroll
            for (int g = 0; g < 16; ++g) { sR[g] = 0.f; sI[g] = 0.f; }
            cmm32_tile2<PSZ, PSZ>(XR, XT, arow32, bcol32, khalf, sR, sI);
        }
        __syncthreads();   // all P reads (riders + frags) complete
        if (wv < 4) {
            store_P_vals32(XR, XT, ti2*32, tj2*32, lane, sR, sI);
        }
        __syncthreads();
    }
    // P = dA^512 ; XF rows 0..63 = x_i ; Gm rows 0..7 = g_0..g_7

    // ---- tail tt = 0..3: chained dA^512 G-steps + K tiles (direct global) ----
    // G rows [8+8tt, 24+8tt) <- A rows [8tt, 8tt+16) (out row 8+ab+m depends
    // only on A row ab+m, so in-interval row overlap is benign).
#pragma unroll 1
    for (int tt = 0; tt < 4; ++tt) {
        if (tt < 3 && wv < 4) {
            const int ab = tt * 8;
            float4_t aP = z4, aN = z4, aI1 = z4, aI2 = z4;
            cmm_tile<GSZ, PSZ, true>(Gm, XT, ab + fm, wv*16 + fm, fq, aP, aN, aI1, aI2);
#pragma unroll
            for (int r = 0; r < 4; ++r) {
                int orow = 8 + ab + fq*4 + r;
                if (orow < 32) {
                    int oc = wv*16 + fm;
                    unsigned hb, lb;
                    split2(aP[r] - aN[r], hb, lb);
                    Gm[orow*RS + oc]       = (u16)(hb >> 16);
                    Gm[GSZ + orow*RS + oc] = (u16)(lb >> 16);
                    split2(aI1[r] + aI2[r], hb, lb);
                    Gm[2*GSZ + orow*RS + oc] = (u16)(hb >> 16);
                    Gm[3*GSZ + orow*RS + oc] = (u16)(lb >> 16);
                }
            }
        }
        if (wv >= 4 && wv < 8) {           // K rows [8tt, 8tt+8): direct global store
            const int jb = tt * 8;
            // clamp A row inside Gm's 32 rows (rows >= 32 feed only discarded C rows)
            int ga = jb + fm; if (ga > 31) ga = 31;
            float4_t aP = z4, aN = z4, aI1 = z4, aI2 = z4;
            cmm_tile<GSZ, PSZ, false>(Gm, XF, ga, (wv-4)*16 + fm, fq, aP, aN, aI1, aI2);
            if (fq < 2) {
                size_t base = (size_t)h * LSEQ;
#pragma unroll
                for (int r = 0; r < 4; ++r)
                    outp[base + (jb + fq*4 + r)*NN + (wv-4)*16 + fm] = aP[r] - aN[r];
            }
        }
        if (tt < 3) __syncthreads();
    }
}

extern "C" void kernel_launch(void* const* d_in, const int* in_sizes, int n_in,
                              void* d_out, int out_size, void* d_ws, size_t ws_size,
                              hipStream_t stream) {
    const float* A  = (const float*)d_in[0];
    const float* B  = (const float*)d_in[1];
    const float* C  = (const float*)d_in[2];
    const float* ld = (const float*)d_in[3];
    float* out = (float*)d_out;
    ssm_kernel<<<dim3(NH), dim3(NTH), 0, stream>>>(A, B, C, ld, out);
}